// Round 6
// baseline (90.268 us; speedup 1.0000x reference)
//
#include <hip/hip_runtime.h>
#include <math.h>

#define NTOK 16384
#define D_   2048
#define E_   64
#define TPB  64            // tokens per block
#define NKC  (D_/32)       // 64 k32-steps

typedef _Float16 f16x8 __attribute__((ext_vector_type(8)));
typedef float    f32x4 __attribute__((ext_vector_type(4)));

#define LSCALE      256.0f          // pre-scale x and W before f16 split (denorm guard)
#define LSCALE2_INV (1.0f/65536.0f) // exact pow2 un-scale of acc

#define LOG_STRIDE 65
#define RES_OFF    (TPB*LOG_STRIDE)       // 4160
#define SMEM_FLOATS (RES_OFF + TPB*4)     // 4416 floats = 17.7 KB

// ---- Kernel 1: W (E x D fp32) -> fragment-ordered f16 hi/lo, scaled x256 ----
// Fragment order: element j of lane l for (n-tile nt, k32-step kc) is
//   W[e = nt*16 + (l&15)][k = kc*32 + (l>>4)*4 + (j&3) + (j>=4 ? 16 : 0)]
// The SAME k-map is used for the A operand, so any deviation from the true
// HW k-order cancels in the contraction.
__global__ __launch_bounds__(256)
void prep_w(const float* __restrict__ W,
            _Float16* __restrict__ wh, _Float16* __restrict__ wl)
{
    const int idx = blockIdx.x * 256 + threadIdx.x;   // 0..16383
    const int l  = idx & 63;
    const int kc = (idx >> 6) & 63;
    const int nt = idx >> 12;                          // 0..3
    const int e  = nt * 16 + (l & 15);
    const int g  = l >> 4;
    const float* src = W + (size_t)e * D_ + kc * 32 + g * 4;
    const float4 f0 = *reinterpret_cast<const float4*>(src);
    const float4 f1 = *reinterpret_cast<const float4*>(src + 16);
    const float v[8] = {f0.x, f0.y, f0.z, f0.w, f1.x, f1.y, f1.z, f1.w};
    f16x8 h, lo;
#pragma unroll
    for (int j = 0; j < 8; ++j) {
        const float vs = v[j] * LSCALE;
        const _Float16 hj = (_Float16)vs;
        h[j]  = hj;
        lo[j] = (_Float16)(vs - (float)hj);
    }
    *reinterpret_cast<f16x8*>(wh + (size_t)idx * 8) = h;
    *reinterpret_cast<f16x8*>(wl + (size_t)idx * 8) = lo;
}

// split a float8 (two float4) into f16 hi/lo fragments, then 3-term MFMA.
// Accumulation order (hh, lh, hl) is IDENTICAL to round 5 -> bitwise-same
// logits (validated: absmax 1.0 < 1.26 threshold).
__device__ __forceinline__ void split_mfma(const float4& xa, const float4& xb,
                                           const f16x8& bh, const f16x8& bl,
                                           f32x4& acc)
{
    const float av[8] = {xa.x, xa.y, xa.z, xa.w, xb.x, xb.y, xb.z, xb.w};
    f16x8 ah, al;
#pragma unroll
    for (int j = 0; j < 8; ++j) {
        const float vs = av[j] * LSCALE;
        const _Float16 hj = (_Float16)vs;
        ah[j] = hj;
        al[j] = (_Float16)(vs - (float)hj);
    }
    acc = __builtin_amdgcn_mfma_f32_16x16x32_f16(ah, bh, acc, 0, 0, 0);
    acc = __builtin_amdgcn_mfma_f32_16x16x32_f16(al, bh, acc, 0, 0, 0);
    acc = __builtin_amdgcn_mfma_f32_16x16x32_f16(ah, bl, acc, 0, 0, 0);
}

// ---- Kernel 2: MFMA router ----
// 256 blocks x 1024 threads (16 waves, 1 block/CU -> 50% occupancy).
// Wave w: m-tile mt = w>>2 (16 tokens), n-tile nt = w&3 (16 experts).
// One 16x16 C tile per wave, full K -> no cross-wave reduction, NO barrier
// in the K-loop (round 5's per-iter __syncthreads serialized load latency).
// 1-deep register prefetch: loads for kc+1 issue before kc's compute.
__global__ __launch_bounds__(1024, 4)
void router_mfma(const float* __restrict__ x,
                 const _Float16* __restrict__ wh,
                 const _Float16* __restrict__ wl,
                 const float* __restrict__ bias,
                 float* __restrict__ out)
{
    __shared__ float smem[SMEM_FLOATS];   // logits [64][65] + res [64][4]

    const int tid = threadIdx.x;
    const int l   = tid & 63;
    const int w   = __builtin_amdgcn_readfirstlane(tid >> 6);
    const int mt  = w >> 2;               // 0..3
    const int nt  = w & 3;                // 0..3
    const int T0  = blockIdx.x * TPB;
    const int g   = l >> 4;

    const float* xp = x + (size_t)(T0 + mt * 16 + (l & 15)) * D_ + g * 4;
    const _Float16* bhp = wh + ((size_t)nt * NKC * 64 + l) * 8;
    const _Float16* blp = wl + ((size_t)nt * NKC * 64 + l) * 8;

    f32x4 acc = {0.f, 0.f, 0.f, 0.f};

    // prologue: load kc=0
    float4 xa_c = *reinterpret_cast<const float4*>(xp);
    float4 xb_c = *reinterpret_cast<const float4*>(xp + 16);
    f16x8  bh_c = *reinterpret_cast<const f16x8*>(bhp);
    f16x8  bl_c = *reinterpret_cast<const f16x8*>(blp);

#pragma unroll 2
    for (int kc = 0; kc < NKC - 1; ++kc) {
        // prefetch kc+1 (issues before the dependent MFMA chain below)
        const float4 xa_n = *reinterpret_cast<const float4*>(xp + (kc+1) * 32);
        const float4 xb_n = *reinterpret_cast<const float4*>(xp + (kc+1) * 32 + 16);
        const f16x8  bh_n = *reinterpret_cast<const f16x8*>(bhp + (size_t)(kc+1) * 512);
        const f16x8  bl_n = *reinterpret_cast<const f16x8*>(blp + (size_t)(kc+1) * 512);

        split_mfma(xa_c, xb_c, bh_c, bl_c, acc);

        xa_c = xa_n; xb_c = xb_n; bh_c = bh_n; bl_c = bl_n;
    }
    split_mfma(xa_c, xb_c, bh_c, bl_c, acc);   // kc = NKC-1

    // ---- C tile -> LDS logits. C layout: col = lane&15, row = (lane>>4)*4 + r ----
    {
        const int row0 = mt * 16 + g * 4;
        const int col0 = nt * 16 + (l & 15);
#pragma unroll
        for (int r = 0; r < 4; ++r)
            smem[(row0 + r) * LOG_STRIDE + col0] = acc[r] * LSCALE2_INV;
    }
    __syncthreads();

    // ---- top-2 + 2-way softmax: thread t scans token t's 64 logits ----
    float* res = smem + RES_OFF;
    if (tid < TPB) {
        const int t = tid;
        float m1 = -INFINITY, m2 = -INFINITY;
        int i1 = 0, i2 = 0;
        for (int e = 0; e < E_; ++e) {
            const float v = smem[t * LOG_STRIDE + e] + bias[e];
            if (v > m1)      { m2 = m1; i2 = i1; m1 = v; i1 = e; }
            else if (v > m2) { m2 = v;  i2 = e; }
        }
        const float ex  = expf(m2 - m1);
        const float den = 1.f + ex;
        res[t*4+0] = 1.f / den;
        res[t*4+1] = ex / den;
        res[t*4+2] = (float)i1;
        res[t*4+3] = (float)i2;
    }
    __syncthreads();

    // ---- coalesced output: probs (64 tokens x 64 experts) ----
    const size_t obase = (size_t)T0 * E_;
#pragma unroll
    for (int i = 0; i < (TPB * E_) / 1024; ++i) {   // 4 iters
        const int f = i * 1024 + tid;
        const int t = f >> 6;
        const int e = f & 63;
        const float p1 = res[t*4+0];
        const float p2 = res[t*4+1];
        const int   i1 = (int)res[t*4+2];
        const int   i2 = (int)res[t*4+3];
        float v = 0.f;
        if (e == i1)      v = p1;
        else if (e == i2) v = p2;
        out[obase + f] = v;
    }
    // ids as float values (whole d_out is read as float32)
    if (tid < TPB * 2) {
        out[(size_t)NTOK * E_ + (size_t)T0 * 2 + tid] =
            res[(tid >> 1) * 4 + 2 + (tid & 1)];
    }
}

extern "C" void kernel_launch(void* const* d_in, const int* in_sizes, int n_in,
                              void* d_out, int out_size, void* d_ws, size_t ws_size,
                              hipStream_t stream) {
    const float* x = (const float*)d_in[0];
    const float* W = (const float*)d_in[1];
    const float* b = (const float*)d_in[2];
    float* out     = (float*)d_out;
    _Float16* wh   = (_Float16*)d_ws;                       // 256 KB
    _Float16* wl   = wh + (size_t)4 * NKC * 64 * 8;         // +256 KB

    hipLaunchKernelGGL(prep_w, dim3(64), dim3(256), 0, stream, W, wh, wl);
    hipLaunchKernelGGL(router_mfma, dim3(NTOK / TPB), dim3(1024), 0, stream,
                       x, wh, wl, b, out);
}

// Round 7
// 57.105 us; speedup vs baseline: 1.5807x; 1.5807x over previous
//
#include <hip/hip_runtime.h>
#include <math.h>

#define NTOK 16384
#define D_   2048
#define E_   64
#define TPB  32            // tokens per block
#define NKC  (D_/32)       // 64 k32-steps

typedef _Float16 f16x8 __attribute__((ext_vector_type(8)));
typedef float    f32x4 __attribute__((ext_vector_type(4)));

#define LSCALE      256.0f          // pre-scale x and W before f16 split (denorm guard)
#define LSCALE2_INV (1.0f/65536.0f) // exact pow2 un-scale of acc

// LDS byte map: 4 staging buffers of 12288 B each at k*12288:
//   x chunk  4096 B  ([32 rows][128 B], slot XOR-swizzled by row&7)
//   bh chunk 4096 B  at +4096 ([4 nt][1024 B], linear fragment order)
//   bl chunk 4096 B  at +8192
// logits [32][65] f32 at 49152 (floats 12288..14367)
// res    [32][4]  f32 at 57472 (floats 14368..14495)
#define BUF_BYTES   12288
#define LOG_OFF_F   12288
#define LOG_STRIDE  65
#define RES_OFF_F   (LOG_OFF_F + TPB*LOG_STRIDE)
#define SMEM_FLOATS (RES_OFF_F + TPB*4)   // 14496 floats = 57984 B

// ---- Kernel 1: W (E x D fp32) -> fragment-ordered f16 hi/lo, scaled x256 ----
// Fragment order: element j of lane l for (n-tile nt, k32-step kc) is
//   W[e = nt*16 + (l&15)][k = kc*32 + (l>>4)*4 + (j&3) + (j>=4 ? 16 : 0)]
// Same k-map as the A operand -> any deviation from HW k-order cancels.
__global__ __launch_bounds__(256)
void prep_w(const float* __restrict__ W,
            _Float16* __restrict__ wh, _Float16* __restrict__ wl)
{
    const int idx = blockIdx.x * 256 + threadIdx.x;   // 0..16383
    const int l  = idx & 63;
    const int kc = (idx >> 6) & 63;
    const int nt = idx >> 12;                          // 0..3
    const int e  = nt * 16 + (l & 15);
    const int g  = l >> 4;
    const float* src = W + (size_t)e * D_ + kc * 32 + g * 4;
    const float4 f0 = *reinterpret_cast<const float4*>(src);
    const float4 f1 = *reinterpret_cast<const float4*>(src + 16);
    const float v[8] = {f0.x, f0.y, f0.z, f0.w, f1.x, f1.y, f1.z, f1.w};
    f16x8 h, lo;
#pragma unroll
    for (int j = 0; j < 8; ++j) {
        const float vs = v[j] * LSCALE;
        const _Float16 hj = (_Float16)vs;
        h[j]  = hj;
        lo[j] = (_Float16)(vs - (float)hj);
    }
    *reinterpret_cast<f16x8*>(wh + (size_t)idx * 8) = h;
    *reinterpret_cast<f16x8*>(wl + (size_t)idx * 8) = lo;
}

__device__ __forceinline__ void stage16(const void* g, void* l) {
    __builtin_amdgcn_global_load_lds(
        (const __attribute__((address_space(1))) void*)g,
        (__attribute__((address_space(3))) void*)l, 16, 0, 0);
}

// ---- Kernel 2: MFMA router, staged-LDS 4-deep async pipeline ----
// 512 blocks x 256 threads (4 waves, 32 tokens, 2 blocks/CU).
// Wave w: mt = w>>1 (16 tokens), nt-pair = w&1 (experts (w&1)*32..+31).
// Per kc: block stages x(4KB, once) + bh/bl(8KB) into LDS via global_load_lds;
// counted s_waitcnt vmcnt(6) keeps 3 stages (9 KB/wave) in flight (T3+T4).
// Per-tile MFMA order (hh,lh,hl; kc ascending) bitwise-matches rounds 5/6.
__global__ __launch_bounds__(256, 4)
void router_mfma(const float* __restrict__ x,
                 const _Float16* __restrict__ wh,
                 const _Float16* __restrict__ wl,
                 const float* __restrict__ bias,
                 float* __restrict__ out)
{
    __shared__ float smem[SMEM_FLOATS];
    char* sb = (char*)smem;

    const int tid = threadIdx.x;
    const int l   = tid & 63;
    const int w   = __builtin_amdgcn_readfirstlane(tid >> 6);  // 0..3
    const int mt  = w >> 1;
    const int nt0 = (w & 1) * 2;
    const int nt1 = nt0 + 1;
    const int T0  = blockIdx.x * TPB;
    const int g   = l >> 4;

    f32x4 acc0 = {0.f, 0.f, 0.f, 0.f};
    f32x4 acc1 = {0.f, 0.f, 0.f, 0.f};

    // staging addresses (wave w stages x rows 8w..8w+7 and nt=w's B fragments)
    const int srow  = (w << 3) + (l >> 3);            // x row this lane feeds
    const int sslot = (l & 7) ^ (srow & 7);           // XOR pre-swizzled source slot
    const float* xsrc0 = x + (size_t)(T0 + srow) * D_ + sslot * 4;
    const _Float16* bhsrc0 = wh + ((size_t)w * NKC * 64 + l) * 8;
    const _Float16* blsrc0 = wl + ((size_t)w * NKC * 64 + l) * 8;
    const int xdst_off  = (w << 10);                  // + lane*16 implicit
    const int bhdst_off = 4096 + (w << 10);
    const int bldst_off = 8192 + (w << 10);

    auto STAGE = [&](int kc) {
        char* bb = sb + (kc & 3) * BUF_BYTES;
        stage16(xsrc0  + kc * 32,          bb + xdst_off);
        stage16(bhsrc0 + (size_t)kc * 512, bb + bhdst_off);
        stage16(blsrc0 + (size_t)kc * 512, bb + bldst_off);
    };

    const int arow = mt * 16 + (l & 15);              // A-fragment token row
    const int r7   = arow & 7;
    const int xa_off = arow * 128 + ((g       ^ r7) << 4);
    const int xb_off = arow * 128 + (((4 + g) ^ r7) << 4);

    auto COMPUTE = [&](int kc) {
        const char* bb = sb + (kc & 3) * BUF_BYTES;
        const float4 xa = *reinterpret_cast<const float4*>(bb + xa_off);
        const float4 xb = *reinterpret_cast<const float4*>(bb + xb_off);
        const f16x8 bh0 = *reinterpret_cast<const f16x8*>(bb + 4096 + nt0 * 1024 + (l << 4));
        const f16x8 bl0 = *reinterpret_cast<const f16x8*>(bb + 8192 + nt0 * 1024 + (l << 4));
        const f16x8 bh1 = *reinterpret_cast<const f16x8*>(bb + 4096 + nt1 * 1024 + (l << 4));
        const f16x8 bl1 = *reinterpret_cast<const f16x8*>(bb + 8192 + nt1 * 1024 + (l << 4));
        const float av[8] = {xa.x, xa.y, xa.z, xa.w, xb.x, xb.y, xb.z, xb.w};
        f16x8 ah, al_;
#pragma unroll
        for (int j = 0; j < 8; ++j) {
            const float vs = av[j] * LSCALE;
            const _Float16 hj = (_Float16)vs;
            ah[j]  = hj;
            al_[j] = (_Float16)(vs - (float)hj);
        }
        acc0 = __builtin_amdgcn_mfma_f32_16x16x32_f16(ah,  bh0, acc0, 0, 0, 0);
        acc0 = __builtin_amdgcn_mfma_f32_16x16x32_f16(al_, bh0, acc0, 0, 0, 0);
        acc0 = __builtin_amdgcn_mfma_f32_16x16x32_f16(ah,  bl0, acc0, 0, 0, 0);
        acc1 = __builtin_amdgcn_mfma_f32_16x16x32_f16(ah,  bh1, acc1, 0, 0, 0);
        acc1 = __builtin_amdgcn_mfma_f32_16x16x32_f16(al_, bh1, acc1, 0, 0, 0);
        acc1 = __builtin_amdgcn_mfma_f32_16x16x32_f16(ah,  bl1, acc1, 0, 0, 0);
    };

    // ---- pipeline: 3 stages in flight, counted vmcnt, 1 barrier/iter ----
    STAGE(0); STAGE(1); STAGE(2);
    for (int kc = 0; kc < NKC - 3; ++kc) {
        asm volatile("s_waitcnt vmcnt(6)" ::: "memory");   // buf[kc] ready
        __builtin_amdgcn_s_barrier();
        STAGE(kc + 3);        // overwrites buf[kc-1]: fully consumed pre-barrier
        COMPUTE(kc);
    }
    asm volatile("s_waitcnt vmcnt(6)" ::: "memory");
    __builtin_amdgcn_s_barrier();
    COMPUTE(NKC - 3);
    asm volatile("s_waitcnt vmcnt(3)" ::: "memory");
    __builtin_amdgcn_s_barrier();
    COMPUTE(NKC - 2);
    asm volatile("s_waitcnt vmcnt(0)" ::: "memory");
    __builtin_amdgcn_s_barrier();
    COMPUTE(NKC - 1);

    // ---- C tiles -> LDS logits. C layout: col = lane&15, row = (lane>>4)*4 + r ----
    {
        float* logits = smem + LOG_OFF_F;
        const int row0 = mt * 16 + g * 4;
        const int c0   = nt0 * 16 + (l & 15);
        const int c1   = nt1 * 16 + (l & 15);
#pragma unroll
        for (int r = 0; r < 4; ++r) {
            logits[(row0 + r) * LOG_STRIDE + c0] = acc0[r] * LSCALE2_INV;
            logits[(row0 + r) * LOG_STRIDE + c1] = acc1[r] * LSCALE2_INV;
        }
    }
    __syncthreads();

    // ---- top-2 + 2-way softmax: thread t scans token t's 64 logits ----
    float* res = smem + RES_OFF_F;
    if (tid < TPB) {
        const float* lg = smem + LOG_OFF_F + tid * LOG_STRIDE;
        float m1 = -INFINITY, m2 = -INFINITY;
        int i1 = 0, i2 = 0;
        for (int e = 0; e < E_; ++e) {
            const float v = lg[e] + bias[e];
            if (v > m1)      { m2 = m1; i2 = i1; m1 = v; i1 = e; }
            else if (v > m2) { m2 = v;  i2 = e; }
        }
        const float ex  = expf(m2 - m1);
        const float den = 1.f + ex;
        res[tid*4+0] = 1.f / den;
        res[tid*4+1] = ex / den;
        res[tid*4+2] = (float)i1;
        res[tid*4+3] = (float)i2;
    }
    __syncthreads();

    // ---- coalesced output: probs (32 tokens x 64 experts) ----
    const size_t obase = (size_t)T0 * E_;
#pragma unroll
    for (int i = 0; i < (TPB * E_) / 256; ++i) {   // 8 iters
        const int f = i * 256 + tid;
        const int t = f >> 6;
        const int e = f & 63;
        const float p1 = res[t*4+0];
        const float p2 = res[t*4+1];
        const int   i1 = (int)res[t*4+2];
        const int   i2 = (int)res[t*4+3];
        float v = 0.f;
        if (e == i1)      v = p1;
        else if (e == i2) v = p2;
        out[obase + f] = v;
    }
    // ids as float values (whole d_out is read as float32)
    if (tid < TPB * 2) {
        out[(size_t)NTOK * E_ + (size_t)T0 * 2 + tid] =
            res[(tid >> 1) * 4 + 2 + (tid & 1)];
    }
}

extern "C" void kernel_launch(void* const* d_in, const int* in_sizes, int n_in,
                              void* d_out, int out_size, void* d_ws, size_t ws_size,
                              hipStream_t stream) {
    const float* x = (const float*)d_in[0];
    const float* W = (const float*)d_in[1];
    const float* b = (const float*)d_in[2];
    float* out     = (float*)d_out;
    _Float16* wh   = (_Float16*)d_ws;                       // 256 KB
    _Float16* wl   = wh + (size_t)4 * NKC * 64 * 8;         // +256 KB

    hipLaunchKernelGGL(prep_w, dim3(64), dim3(256), 0, stream, W, wh, wl);
    hipLaunchKernelGGL(router_mfma, dim3(NTOK / TPB), dim3(256), 0, stream,
                       x, wh, wl, b, out);
}